// Round 8
// baseline (287.820 us; speedup 1.0000x reference)
//
#include <hip/hip_runtime.h>

typedef __attribute__((ext_vector_type(8))) short s16x8;
typedef __attribute__((ext_vector_type(4))) short s16x4;
typedef __attribute__((ext_vector_type(4))) float f32x4;
typedef __attribute__((ext_vector_type(2))) unsigned u32x2;

#define MFMA32(a, b, c) __builtin_amdgcn_mfma_f32_16x16x32_bf16((a), (b), (c), 0, 0, 0)

// Device pass on gfx950 has the 1k builtin (verified rounds 2-7). Host pass
// only parses device code, so stub it there.
#if __has_builtin(__builtin_amdgcn_mfma_f32_16x16x16bf16_1k)
#define MFMA16K(a, b, c) __builtin_amdgcn_mfma_f32_16x16x16bf16_1k((a), (b), (c), 0, 0, 0)
#else
#define MFMA16K(a, b, c) (c) /* host-pass parse stub; never executed */
#endif

#if __has_builtin(__builtin_amdgcn_exp2f)
#define EXP2F(x) __builtin_amdgcn_exp2f(x)
#else
#define EXP2F(x) __exp2f(x)
#endif

#if __has_builtin(__builtin_amdgcn_rcpf)
#define RCPF(x) __builtin_amdgcn_rcpf(x)
#else
#define RCPF(x) (1.0f / (x))
#endif

#define SL2E 0.25507313f  // (1/sqrt(32)) * log2(e)

// pack two f32 -> bf16 pair (RNE)
__device__ __forceinline__ unsigned pkrne(float a, float b) {
  unsigned ua = __builtin_bit_cast(unsigned, a);
  unsigned ub = __builtin_bit_cast(unsigned, b);
  ua += 0x7FFFu + ((ua >> 16) & 1u);
  ub += 0x7FFFu + ((ub >> 16) & 1u);
  return __builtin_amdgcn_perm(ub, ua, 0x07060302u);
}

// pack two f32 -> bf16 pair by TRUNCATION (1 v_perm); bias cancels in p/l
// because l comes from the same truncated P via ones-MFMA.
__device__ __forceinline__ unsigned pktrunc(float a, float b) {
  return __builtin_amdgcn_perm(__builtin_bit_cast(unsigned, b),
                               __builtin_bit_cast(unsigned, a), 0x07060302u);
}

__device__ __forceinline__ unsigned short bfr(float f) {
  unsigned u = __builtin_bit_cast(unsigned, f);
  u += 0x7FFFu + ((u >> 16) & 1u);
  return (unsigned short)(u >> 16);
}

// unpack bf16 pair (packed by pkrne) -> f32
__device__ __forceinline__ float bflo(unsigned u) {
  return __builtin_bit_cast(float, u << 16);
}
__device__ __forceinline__ float bfhi(unsigned u) {
  return __builtin_bit_cast(float, u & 0xFFFF0000u);
}

// ---------------------------------------------------------------------------
// Prep: transpose+convert fp32 sources into bf16 k-contiguous layouts.
// ---------------------------------------------------------------------------
__global__ __launch_bounds__(256) void prep_kernel(
    const float* __restrict__ x, const float* __restrict__ wqkv,
    const float* __restrict__ wout, ushort* __restrict__ xbf,
    ushort* __restrict__ wT, ushort* __restrict__ woT) {
  const int t = threadIdx.x;
  const int sub = t & 15, grp = t >> 4;
  const int id = blockIdx.x;
  const float* src;
  ushort* dst;
  int src_ld, k0, n0;
  float sc = 1.f;
  if (id < 512) {
    int mt = id & 63, kt = (id >> 6) & 3, b = id >> 8;
    src = x + (size_t)b * 256 * 4096;
    src_ld = 4096;
    dst = xbf + (size_t)b * 4096 * 256;
    k0 = kt * 64;
    n0 = mt * 64;
  } else if (id < 560) {
    int r = id - 512, nt = r % 12, kt = r / 12;
    src = wqkv;
    src_ld = 768;
    dst = wT;
    k0 = kt * 64;
    n0 = nt * 64;
    if (n0 < 256) sc = SL2E;
  } else {
    int r = id - 560, nt = r & 3, kt = r >> 2;
    src = wout;
    src_ld = 256;
    dst = woT;
    k0 = kt * 64;
    n0 = nt * 64;
  }
  const int k = k0 + grp * 4;
  const int n = n0 + sub * 4;
  unsigned d0[4], d1[4];
#pragma unroll
  for (int i = 0; i < 4; ++i) {
    float4 v = *(const float4*)(src + (size_t)(k + i) * src_ld + n);
    d0[i] = pkrne(v.x * sc, v.y * sc);
    d1[i] = pkrne(v.z * sc, v.w * sc);
  }
  u32x2 r0 = {__builtin_amdgcn_perm(d0[1], d0[0], 0x05040100u),
              __builtin_amdgcn_perm(d0[3], d0[2], 0x05040100u)};
  u32x2 r1 = {__builtin_amdgcn_perm(d0[1], d0[0], 0x07060302u),
              __builtin_amdgcn_perm(d0[3], d0[2], 0x07060302u)};
  u32x2 r2 = {__builtin_amdgcn_perm(d1[1], d1[0], 0x05040100u),
              __builtin_amdgcn_perm(d1[3], d1[2], 0x05040100u)};
  u32x2 r3 = {__builtin_amdgcn_perm(d1[1], d1[0], 0x07060302u),
              __builtin_amdgcn_perm(d1[3], d1[2], 0x07060302u)};
  *(u32x2*)(dst + (size_t)(n + 0) * 256 + k) = r0;
  *(u32x2*)(dst + (size_t)(n + 1) * 256 + k) = r1;
  *(u32x2*)(dst + (size_t)(n + 2) * 256 + k) = r2;
  *(u32x2*)(dst + (size_t)(n + 3) * 256 + k) = r3;
}

// ---------------------------------------------------------------------------
// Fused QKV: D[n][tok] = wT(rows n) x xbf(rows tok). (unchanged, round 6)
// ---------------------------------------------------------------------------
__global__ __launch_bounds__(256) void qkv_kernel(
    const ushort* __restrict__ xbf, const ushort* __restrict__ wT,
    const float* __restrict__ bq, ushort* __restrict__ QG,
    ushort* __restrict__ KG, ushort* __restrict__ VtG) {
  __shared__ __align__(16) ushort Wl[64][40];
  __shared__ __align__(16) ushort Xl[128][40];
  const int t0 = blockIdx.x * 128;
  const int n0 = blockIdx.y * 64;
  const int t = threadIdx.x;
  const int wid = t >> 6, lane = t & 63;
  const int wy = wid >> 1, wx = wid & 1;
  const int quad = lane >> 4, l16 = lane & 15;
  f32x4 acc[2][4] = {};
  const int wr = t >> 2, wsg = t & 3;
  for (int k0 = 0; k0 < 256; k0 += 32) {
    __syncthreads();
    *(uint4*)&Wl[wr][wsg * 8] =
        *(const uint4*)(wT + (size_t)(n0 + wr) * 256 + k0 + wsg * 8);
#pragma unroll
    for (int i = 0; i < 2; ++i) {
      int fid = t + 256 * i, row = fid >> 2, seg = fid & 3;
      *(uint4*)&Xl[row][seg * 8] =
          *(const uint4*)(xbf + (size_t)(t0 + row) * 256 + k0 + seg * 8);
    }
    __syncthreads();
    s16x8 wf[2], xf[4];
#pragma unroll
    for (int i = 0; i < 2; ++i)
      wf[i] = *(const s16x8*)&Wl[32 * wy + 16 * i + l16][quad * 8];
#pragma unroll
    for (int j = 0; j < 4; ++j)
      xf[j] = *(const s16x8*)&Xl[64 * wx + 16 * j + l16][quad * 8];
#pragma unroll
    for (int i = 0; i < 2; ++i)
#pragma unroll
      for (int j = 0; j < 4; ++j) acc[i][j] = MFMA32(wf[i], xf[j], acc[i][j]);
  }
  if (n0 < 512) {
    ushort* dst = (n0 < 256) ? QG : KG;
    const float bsc = (n0 < 256) ? SL2E : 1.f;
#pragma unroll
    for (int i = 0; i < 2; ++i) {
      int nb = n0 + 32 * wy + 16 * i + 4 * quad;
      float4 b4 = *(const float4*)(bq + nb);
      float bx0 = b4.x * bsc, bx1 = b4.y * bsc, bx2 = b4.z * bsc,
            bx3 = b4.w * bsc;
      int h = ((nb & 255) >> 5);
      int dd0 = nb & 31;
#pragma unroll
      for (int j = 0; j < 4; ++j) {
        int tok = t0 + 64 * wx + 16 * j + l16;
        int b = tok >> 12, tokn = tok & 4095;
        u32x2 pk = {pkrne(acc[i][j][0] + bx0, acc[i][j][1] + bx1),
                    pkrne(acc[i][j][2] + bx2, acc[i][j][3] + bx3)};
        *(u32x2*)(dst + ((size_t)(b * 8 + h) * 4096 + tokn) * 32 + dd0) = pk;
      }
    }
  } else {
#pragma unroll
    for (int i = 0; i < 2; ++i) {
      int nb = n0 + 32 * wy + 16 * i + 4 * quad;
      float4 b4 = *(const float4*)(bq + nb);
      float bb[4] = {b4.x, b4.y, b4.z, b4.w};
#pragma unroll
      for (int r = 0; r < 4; ++r) {
        int nn = nb + r - 512;
        int h = nn >> 5, ddv = nn & 31;
        ushort* vrow = VtG + (size_t)(h * 32 + ddv) * 4096;
#pragma unroll
        for (int j = 0; j < 4; ++j) {
          int tok = t0 + 64 * wx + 16 * j + l16;
          int b = tok >> 12, tokn = tok & 4095;
          vrow[(size_t)b * 8 * 32 * 4096 + tokn] = bfr(acc[i][j][r] + bb[r]);
        }
      }
    }
  }
}

// ---------------------------------------------------------------------------
// Flash attention, SPLIT-K x4. Grid 2048 -> 8 blocks/CU (LDS 19456B x 8 =
// 155.6 of 160 KiB; VGPR<=64 via launch_bounds(256,8)). Block (bh, q128, sp)
// handles k-tiles [sp*16, sp*16+16). No-max softmax => partials additive.
// Partial O stored bf16 (pkrne; error after combine ~6e-5), partial l f32.
// ---------------------------------------------------------------------------
__global__ __launch_bounds__(256, 8) void attn_split(
    const ushort* __restrict__ QG, const ushort* __restrict__ KG,
    const ushort* __restrict__ VtG, ushort* __restrict__ OF0,
    ushort* __restrict__ OFb, float* __restrict__ LF) {
  __shared__ __align__(16) ushort Kl[2][64][40];
  __shared__ __align__(16) ushort Vl[2][32][72];
  const int id = blockIdx.x;
  const int bh = (id & 7) * 2 + ((id >> 3) & 1);  // XCD-affine heads
  const int q0 = ((id >> 4) & 31) * 128;
  const int sp = id >> 9;                          // split index 0..3
  const int kt0 = sp * 16, kt1 = kt0 + 16;
  const int t = threadIdx.x;
  const int wid = t >> 6, lane = t & 63;
  const int quad = lane >> 4, l16 = lane & 15;
  const size_t base = (size_t)bh * 4096 * 32;
  const ushort* qp = QG + base;
  const ushort* kp = KG + base;
  const ushort* vp = VtG + base;
  const int qw = q0 + 32 * wid;
  const s16x8 qf0 = *(const s16x8*)(qp + (size_t)(qw + l16) * 32 + quad * 8);
  const s16x8 qf1 = *(const s16x8*)(qp + (size_t)(qw + 16 + l16) * 32 + quad * 8);
  const int kr = t >> 2, ks = t & 3;
  const int vr = t >> 3, vsg = t & 7;
  *(uint4*)&Kl[0][kr][ks * 8] =
      *(const uint4*)(kp + (size_t)(kt0 * 64 + kr) * 32 + ks * 8);
  *(uint4*)&Vl[0][vr][vsg * 8] =
      *(const uint4*)(vp + (size_t)vr * 4096 + kt0 * 64 + vsg * 8);
  const ushort* kpre = kp + (size_t)((kt0 + 1) * 64 + kr) * 32 + ks * 8;
  const ushort* vpre = vp + (size_t)vr * 4096 + (kt0 + 1) * 64 + vsg * 8;
  __syncthreads();
  f32x4 o00 = {}, o01 = {}, o10 = {}, o11 = {}, ol0 = {}, ol1 = {};
  const f32x4 zero = {};
  const s16x4 ones = {(short)0x3F80, (short)0x3F80, (short)0x3F80,
                      (short)0x3F80};
#pragma unroll 2
  for (int kt = kt0; kt < kt1; ++kt) {
    const int cur = kt & 1;
    const bool more = (kt + 1) < kt1;
    uint4 kv, vv;
    if (more) {
      kv = *(const uint4*)kpre;
      vv = *(const uint4*)vpre;
      kpre += 2048;
      vpre += 64;
    }
    f32x4 st0[4], st1[4];
#pragma unroll
    for (int nb = 0; nb < 4; ++nb) {
      s16x8 kf = *(const s16x8*)&Kl[cur][16 * nb + l16][quad * 8];
      st0[nb] = MFMA32(kf, qf0, zero);
      st1[nb] = MFMA32(kf, qf1, zero);
    }
    unsigned pl0[4], ph0[4], pl1[4], ph1[4];
#pragma unroll
    for (int nb = 0; nb < 4; ++nb) {
      float a0 = EXP2F(st0[nb][0]);
      float a1 = EXP2F(st0[nb][1]);
      float a2 = EXP2F(st0[nb][2]);
      float a3 = EXP2F(st0[nb][3]);
      pl0[nb] = pktrunc(a0, a1);
      ph0[nb] = pktrunc(a2, a3);
      float b0 = EXP2F(st1[nb][0]);
      float b1 = EXP2F(st1[nb][1]);
      float b2 = EXP2F(st1[nb][2]);
      float b3 = EXP2F(st1[nb][3]);
      pl1[nb] = pktrunc(b0, b1);
      ph1[nb] = pktrunc(b2, b3);
    }
#pragma unroll
    for (int nb = 0; nb < 4; ++nb) {
      u32x2 pu0 = {pl0[nb], ph0[nb]};
      u32x2 pu1 = {pl1[nb], ph1[nb]};
      s16x4 pv0 = __builtin_bit_cast(s16x4, pu0);
      s16x4 pv1 = __builtin_bit_cast(s16x4, pu1);
      s16x4 va = *(const s16x4*)&Vl[cur][l16][16 * nb + quad * 4];
      s16x4 vb = *(const s16x4*)&Vl[cur][16 + l16][16 * nb + quad * 4];
      o00 = MFMA16K(va, pv0, o00);
      o01 = MFMA16K(vb, pv0, o01);
      o10 = MFMA16K(va, pv1, o10);
      o11 = MFMA16K(vb, pv1, o11);
      ol0 = MFMA16K(ones, pv0, ol0);
      ol1 = MFMA16K(ones, pv1, ol1);
    }
    if (more) {
      *(uint4*)&Kl[cur ^ 1][kr][ks * 8] = kv;
      *(uint4*)&Vl[cur ^ 1][vr][vsg * 8] = vv;
    }
    __syncthreads();
  }
  // Store un-normalized bf16 partial O + f32 partial l.
  ushort* OFs = (sp == 0) ? OF0 : OFb + (size_t)(sp - 1) * 2097152;
  float* LFs = LF + (size_t)sp * 65536;
  const int tok0 = qw + l16;
  const size_t ob0 = ((size_t)bh * 4096 + tok0) * 32;
  const size_t ob1 = ob0 + (size_t)16 * 32;
  u32x2 w00 = {pkrne(o00[0], o00[1]), pkrne(o00[2], o00[3])};
  u32x2 w01 = {pkrne(o01[0], o01[1]), pkrne(o01[2], o01[3])};
  u32x2 w10 = {pkrne(o10[0], o10[1]), pkrne(o10[2], o10[3])};
  u32x2 w11 = {pkrne(o11[0], o11[1]), pkrne(o11[2], o11[3])};
  *(u32x2*)(OFs + ob0 + 4 * quad) = w00;
  *(u32x2*)(OFs + ob0 + 16 + 4 * quad) = w01;
  *(u32x2*)(OFs + ob1 + 4 * quad) = w10;
  *(u32x2*)(OFs + ob1 + 16 + 4 * quad) = w11;
  if (quad == 0) {
    LFs[(size_t)bh * 4096 + tok0] = ol0[0];
    LFs[(size_t)bh * 4096 + tok0 + 16] = ol1[0];
  }
}

// ---------------------------------------------------------------------------
// Out-proj with fused 4-way split-combine + normalization in the staging.
// ---------------------------------------------------------------------------
__global__ __launch_bounds__(256) void proj_split(
    const ushort* __restrict__ OF0, const ushort* __restrict__ OFb,
    const float* __restrict__ LF, const ushort* __restrict__ woT,
    const float* __restrict__ bo, float* __restrict__ out) {
  __shared__ __align__(16) ushort Wl[64][40];
  __shared__ __align__(16) ushort Xl[128][40];
  const int t0 = blockIdx.x * 128;
  const int c0 = blockIdx.y * 64;
  const int t = threadIdx.x;
  const int wid = t >> 6, lane = t & 63;
  const int wy = wid >> 1, wx = wid & 1;
  const int quad = lane >> 4, l16 = lane & 15;
  f32x4 acc[2][4] = {};
  const int wr = t >> 2, wsg = t & 3;
  const int c8 = (t & 7) * 4;  // dd column (4 ushorts)
  for (int k0 = 0; k0 < 256; k0 += 32) {
    __syncthreads();
    *(uint4*)&Wl[wr][wsg * 8] =
        *(const uint4*)(woT + (size_t)(c0 + wr) * 256 + k0 + wsg * 8);
    const int hh = k0 >> 5;
#pragma unroll
    for (int p = 0; p < 4; ++p) {
      int row = 32 * p + (t >> 3);
      int tok = t0 + row, bb = tok >> 12, tokn = tok & 4095;
      size_t ro = (size_t)(bb * 8 + hh) * 4096 + tokn;
      size_t oi = ro * 32 + c8;
      uint2 a0 = *(const uint2*)(OF0 + oi);
      uint2 a1 = *(const uint2*)(OFb + oi);
      uint2 a2 = *(const uint2*)(OFb + 2097152 + oi);
      uint2 a3 = *(const uint2*)(OFb + 4194304 + oi);
      float l = (LF[ro] + LF[65536 + ro]) + (LF[131072 + ro] + LF[196608 + ro]);
      float inv = RCPF(l);
      f32x4 s;
      s[0] = (bflo(a0.x) + bflo(a1.x)) + (bflo(a2.x) + bflo(a3.x));
      s[1] = (bfhi(a0.x) + bfhi(a1.x)) + (bfhi(a2.x) + bfhi(a3.x));
      s[2] = (bflo(a0.y) + bflo(a1.y)) + (bflo(a2.y) + bflo(a3.y));
      s[3] = (bfhi(a0.y) + bfhi(a1.y)) + (bfhi(a2.y) + bfhi(a3.y));
      s *= inv;
      u32x2 pk = {pkrne(s[0], s[1]), pkrne(s[2], s[3])};
      *(u32x2*)&Xl[row][c8] = pk;
    }
    __syncthreads();
    s16x8 wf[2], xf[4];
#pragma unroll
    for (int i = 0; i < 2; ++i)
      wf[i] = *(const s16x8*)&Wl[32 * wy + 16 * i + l16][quad * 8];
#pragma unroll
    for (int j = 0; j < 4; ++j)
      xf[j] = *(const s16x8*)&Xl[64 * wx + 16 * j + l16][quad * 8];
#pragma unroll
    for (int i = 0; i < 2; ++i)
#pragma unroll
      for (int j = 0; j < 4; ++j) acc[i][j] = MFMA32(wf[i], xf[j], acc[i][j]);
  }
#pragma unroll
  for (int i = 0; i < 2; ++i) {
    int cb = c0 + 32 * wy + 16 * i + 4 * quad;
    float4 b4 = *(const float4*)(bo + cb);
    float bb[4] = {b4.x, b4.y, b4.z, b4.w};
#pragma unroll
    for (int j = 0; j < 4; ++j) {
      int tok = t0 + 64 * wx + 16 * j + l16;
      int b = tok >> 12, tokn = tok & 4095;
#pragma unroll
      for (int r = 0; r < 4; ++r)
        out[((size_t)(b * 256 + cb + r)) * 4096 + tokn] = acc[i][j][r] + bb[r];
    }
  }
}

// ======================= FALLBACK (round-6 verbatim) =======================
__global__ __launch_bounds__(256) void attn_fb(
    const ushort* __restrict__ QG, const ushort* __restrict__ KG,
    const ushort* __restrict__ VtG, ushort* __restrict__ Ob) {
  __shared__ __align__(16) ushort Kl[2][64][40];
  __shared__ __align__(16) ushort Vl[2][32][72];
  const int id = blockIdx.x;
  const int bh = (id & 7) * 2 + ((id >> 3) & 1);
  const int q0 = (id >> 4) * 128;
  const int t = threadIdx.x;
  const int wid = t >> 6, lane = t & 63;
  const int quad = lane >> 4, l16 = lane & 15;
  const size_t base = (size_t)bh * 4096 * 32;
  const ushort* qp = QG + base;
  const ushort* kp = KG + base;
  const ushort* vp = VtG + base;
  const int qw = q0 + 32 * wid;
  const s16x8 qf0 = *(const s16x8*)(qp + (size_t)(qw + l16) * 32 + quad * 8);
  const s16x8 qf1 = *(const s16x8*)(qp + (size_t)(qw + 16 + l16) * 32 + quad * 8);
  const int kr = t >> 2, ks = t & 3;
  const int vr = t >> 3, vsg = t & 7;
  *(uint4*)&Kl[0][kr][ks * 8] = *(const uint4*)(kp + (size_t)kr * 32 + ks * 8);
  *(uint4*)&Vl[0][vr][vsg * 8] = *(const uint4*)(vp + (size_t)vr * 4096 + vsg * 8);
  const ushort* kpre = kp + (size_t)(64 + kr) * 32 + ks * 8;
  const ushort* vpre = vp + (size_t)vr * 4096 + 64 + vsg * 8;
  __syncthreads();
  f32x4 o00 = {}, o01 = {}, o10 = {}, o11 = {}, ol0 = {}, ol1 = {};
  const f32x4 zero = {};
  const s16x4 ones = {(short)0x3F80, (short)0x3F80, (short)0x3F80,
                      (short)0x3F80};
#pragma unroll 2
  for (int kt = 0; kt < 64; ++kt) {
    const int cur = kt & 1;
    const bool more = (kt + 1) < 64;
    uint4 kv, vv;
    if (more) {
      kv = *(const uint4*)kpre;
      vv = *(const uint4*)vpre;
      kpre += 2048;
      vpre += 64;
    }
    f32x4 st0[4], st1[4];
#pragma unroll
    for (int nb = 0; nb < 4; ++nb) {
      s16x8 kf = *(const s16x8*)&Kl[cur][16 * nb + l16][quad * 8];
      st0[nb] = MFMA32(kf, qf0, zero);
      st1[nb] = MFMA32(kf, qf1, zero);
    }
    unsigned pl0[4], ph0[4], pl1[4], ph1[4];
#pragma unroll
    for (int nb = 0; nb < 4; ++nb) {
      float a0 = EXP2F(st0[nb][0]);
      float a1 = EXP2F(st0[nb][1]);
      float a2 = EXP2F(st0[nb][2]);
      float a3 = EXP2F(st0[nb][3]);
      pl0[nb] = pktrunc(a0, a1);
      ph0[nb] = pktrunc(a2, a3);
      float b0 = EXP2F(st1[nb][0]);
      float b1 = EXP2F(st1[nb][1]);
      float b2 = EXP2F(st1[nb][2]);
      float b3 = EXP2F(st1[nb][3]);
      pl1[nb] = pktrunc(b0, b1);
      ph1[nb] = pktrunc(b2, b3);
    }
#pragma unroll
    for (int nb = 0; nb < 4; ++nb) {
      u32x2 pu0 = {pl0[nb], ph0[nb]};
      u32x2 pu1 = {pl1[nb], ph1[nb]};
      s16x4 pv0 = __builtin_bit_cast(s16x4, pu0);
      s16x4 pv1 = __builtin_bit_cast(s16x4, pu1);
      s16x4 va = *(const s16x4*)&Vl[cur][l16][16 * nb + quad * 4];
      s16x4 vb = *(const s16x4*)&Vl[cur][16 + l16][16 * nb + quad * 4];
      o00 = MFMA16K(va, pv0, o00);
      o01 = MFMA16K(vb, pv0, o01);
      o10 = MFMA16K(va, pv1, o10);
      o11 = MFMA16K(vb, pv1, o11);
      ol0 = MFMA16K(ones, pv0, ol0);
      ol1 = MFMA16K(ones, pv1, ol1);
    }
    if (more) {
      *(uint4*)&Kl[cur ^ 1][kr][ks * 8] = kv;
      *(uint4*)&Vl[cur ^ 1][vr][vsg * 8] = vv;
    }
    __syncthreads();
  }
  const float inv0 = 1.0f / ol0[0];
  const float inv1 = 1.0f / ol1[0];
  const int b = bh >> 3, h = bh & 7;
  const int tok0 = qw + l16;
  const size_t row0 = ((size_t)b * 4096 + tok0) * 256 + h * 32;
  const size_t row1 = row0 + (size_t)16 * 256;
  u32x2 w00 = {pkrne(o00[0] * inv0, o00[1] * inv0),
               pkrne(o00[2] * inv0, o00[3] * inv0)};
  u32x2 w01 = {pkrne(o01[0] * inv0, o01[1] * inv0),
               pkrne(o01[2] * inv0, o01[3] * inv0)};
  u32x2 w10 = {pkrne(o10[0] * inv1, o10[1] * inv1),
               pkrne(o10[2] * inv1, o10[3] * inv1)};
  u32x2 w11 = {pkrne(o11[0] * inv1, o11[1] * inv1),
               pkrne(o11[2] * inv1, o11[3] * inv1)};
  *(u32x2*)(Ob + row0 + 4 * quad) = w00;
  *(u32x2*)(Ob + row0 + 16 + 4 * quad) = w01;
  *(u32x2*)(Ob + row1 + 4 * quad) = w10;
  *(u32x2*)(Ob + row1 + 16 + 4 * quad) = w11;
}

__global__ __launch_bounds__(256) void proj_fb(
    const ushort* __restrict__ Ob, const ushort* __restrict__ woT,
    const float* __restrict__ bo, float* __restrict__ out) {
  __shared__ __align__(16) ushort Wl[64][40];
  __shared__ __align__(16) ushort Xl[128][40];
  const int t0 = blockIdx.x * 128;
  const int c0 = blockIdx.y * 64;
  const int t = threadIdx.x;
  const int wid = t >> 6, lane = t & 63;
  const int wy = wid >> 1, wx = wid & 1;
  const int quad = lane >> 4, l16 = lane & 15;
  f32x4 acc[2][4] = {};
  const int wr = t >> 2, wsg = t & 3;
  for (int k0 = 0; k0 < 256; k0 += 32) {
    __syncthreads();
    *(uint4*)&Wl[wr][wsg * 8] =
        *(const uint4*)(woT + (size_t)(c0 + wr) * 256 + k0 + wsg * 8);
#pragma unroll
    for (int i = 0; i < 2; ++i) {
      int fid = t + 256 * i, row = fid >> 2, seg = fid & 3;
      *(uint4*)&Xl[row][seg * 8] =
          *(const uint4*)(Ob + (size_t)(t0 + row) * 256 + k0 + seg * 8);
    }
    __syncthreads();
    s16x8 wf[2], xf[4];
#pragma unroll
    for (int i = 0; i < 2; ++i)
      wf[i] = *(const s16x8*)&Wl[32 * wy + 16 * i + l16][quad * 8];
#pragma unroll
    for (int j = 0; j < 4; ++j)
      xf[j] = *(const s16x8*)&Xl[64 * wx + 16 * j + l16][quad * 8];
#pragma unroll
    for (int i = 0; i < 2; ++i)
#pragma unroll
      for (int j = 0; j < 4; ++j) acc[i][j] = MFMA32(wf[i], xf[j], acc[i][j]);
  }
#pragma unroll
  for (int i = 0; i < 2; ++i) {
    int cb = c0 + 32 * wy + 16 * i + 4 * quad;
    float4 b4 = *(const float4*)(bo + cb);
    float bb[4] = {b4.x, b4.y, b4.z, b4.w};
#pragma unroll
    for (int j = 0; j < 4; ++j) {
      int tok = t0 + 64 * wx + 16 * j + l16;
      int b = tok >> 12, tokn = tok & 4095;
#pragma unroll
      for (int r = 0; r < 4; ++r)
        out[((size_t)(b * 256 + cb + r)) * 4096 + tokn] = acc[i][j][r] + bb[r];
    }
  }
}

extern "C" void kernel_launch(void* const* d_in, const int* in_sizes, int n_in,
                              void* d_out, int out_size, void* d_ws, size_t ws_size,
                              hipStream_t stream) {
  (void)in_sizes; (void)n_in; (void)out_size;
  const float* x = (const float*)d_in[0];
  const float* wq = (const float*)d_in[1];
  const float* bq = (const float*)d_in[2];
  const float* wo = (const float*)d_in[3];
  const float* bo = (const float*)d_in[4];
  float* out = (float*)d_out;
  ushort* ws = (ushort*)d_ws;
  // bf16 core region (17.3 MB):
  ushort* xbf = ws;                    // [8192][256]  (dead after qkv)
  ushort* Ob  = ws;                    // fallback path only
  ushort* OF0 = ws;                    // split0 partial O overlays dead xbf
  ushort* QG  = ws + 2097152;          // [2][8][4096][32]
  ushort* KG  = ws + 4194304;
  ushort* VtG = ws + 6291456;          // [2][8][32][4096]
  ushort* wT  = ws + 8388608;          // [768][256]
  ushort* woT = ws + 8585216;          // [256][256]
  // split partials 1..3 (bf16) + l (f32): ends at byte 30,932,992
  ushort* OFb = ws + 8650752;          // 3 x 2,097,152 ushorts
  float* LF = (float*)(ws + 14942208); // [4][16][4096] f32
  const bool split = ws_size >= 30932992;  // constant per run
  prep_kernel<<<576, 256, 0, stream>>>(x, wq, wo, xbf, wT, woT);
  qkv_kernel<<<dim3(64, 12), 256, 0, stream>>>(xbf, wT, bq, QG, KG, VtG);
  if (split) {
    attn_split<<<2048, 256, 0, stream>>>(QG, KG, VtG, OF0, OFb, LF);
    proj_split<<<dim3(64, 4), 256, 0, stream>>>(OF0, OFb, LF, woT, bo, out);
  } else {
    attn_fb<<<512, 256, 0, stream>>>(QG, KG, VtG, Ob);
    proj_fb<<<dim3(64, 4), 256, 0, stream>>>(Ob, woT, bo, out);
  }
}

// Round 9
// 141.506 us; speedup vs baseline: 2.0340x; 2.0340x over previous
//
#include <hip/hip_runtime.h>

typedef __attribute__((ext_vector_type(8))) short s16x8;
typedef __attribute__((ext_vector_type(4))) short s16x4;
typedef __attribute__((ext_vector_type(4))) float f32x4;
typedef __attribute__((ext_vector_type(2))) unsigned u32x2;

#define MFMA32(a, b, c) __builtin_amdgcn_mfma_f32_16x16x32_bf16((a), (b), (c), 0, 0, 0)

// Device pass on gfx950 has the 1k builtin (verified rounds 2-8). Host pass
// only parses device code, so stub it there.
#if __has_builtin(__builtin_amdgcn_mfma_f32_16x16x16bf16_1k)
#define MFMA16K(a, b, c) __builtin_amdgcn_mfma_f32_16x16x16bf16_1k((a), (b), (c), 0, 0, 0)
#else
#define MFMA16K(a, b, c) (c) /* host-pass parse stub; never executed */
#endif

#if __has_builtin(__builtin_amdgcn_exp2f)
#define EXP2F(x) __builtin_amdgcn_exp2f(x)
#else
#define EXP2F(x) __exp2f(x)
#endif

#if __has_builtin(__builtin_amdgcn_rcpf)
#define RCPF(x) __builtin_amdgcn_rcpf(x)
#else
#define RCPF(x) (1.0f / (x))
#endif

#define SL2E 0.25507313f  // (1/sqrt(32)) * log2(e)

// pack two f32 -> bf16 pair (RNE)
__device__ __forceinline__ unsigned pkrne(float a, float b) {
  unsigned ua = __builtin_bit_cast(unsigned, a);
  unsigned ub = __builtin_bit_cast(unsigned, b);
  ua += 0x7FFFu + ((ua >> 16) & 1u);
  ub += 0x7FFFu + ((ub >> 16) & 1u);
  return __builtin_amdgcn_perm(ub, ua, 0x07060302u);
}

// pack two f32 -> bf16 pair by TRUNCATION (1 v_perm); bias cancels in p/l
// because l comes from the same truncated P via ones-MFMA.
__device__ __forceinline__ unsigned pktrunc(float a, float b) {
  return __builtin_amdgcn_perm(__builtin_bit_cast(unsigned, b),
                               __builtin_bit_cast(unsigned, a), 0x07060302u);
}

__device__ __forceinline__ unsigned short bfr(float f) {
  unsigned u = __builtin_bit_cast(unsigned, f);
  u += 0x7FFFu + ((u >> 16) & 1u);
  return (unsigned short)(u >> 16);
}

// unpack bf16 pair -> f32
__device__ __forceinline__ float bflo(unsigned u) {
  return __builtin_bit_cast(float, u << 16);
}
__device__ __forceinline__ float bfhi(unsigned u) {
  return __builtin_bit_cast(float, u & 0xFFFF0000u);
}

// ---------------------------------------------------------------------------
// Prep: transpose+convert fp32 sources into bf16 k-contiguous layouts.
// ---------------------------------------------------------------------------
__global__ __launch_bounds__(256) void prep_kernel(
    const float* __restrict__ x, const float* __restrict__ wqkv,
    const float* __restrict__ wout, ushort* __restrict__ xbf,
    ushort* __restrict__ wT, ushort* __restrict__ woT) {
  const int t = threadIdx.x;
  const int sub = t & 15, grp = t >> 4;
  const int id = blockIdx.x;
  const float* src;
  ushort* dst;
  int src_ld, k0, n0;
  float sc = 1.f;
  if (id < 512) {
    int mt = id & 63, kt = (id >> 6) & 3, b = id >> 8;
    src = x + (size_t)b * 256 * 4096;
    src_ld = 4096;
    dst = xbf + (size_t)b * 4096 * 256;
    k0 = kt * 64;
    n0 = mt * 64;
  } else if (id < 560) {
    int r = id - 512, nt = r % 12, kt = r / 12;
    src = wqkv;
    src_ld = 768;
    dst = wT;
    k0 = kt * 64;
    n0 = nt * 64;
    if (n0 < 256) sc = SL2E;
  } else {
    int r = id - 560, nt = r & 3, kt = r >> 2;
    src = wout;
    src_ld = 256;
    dst = woT;
    k0 = kt * 64;
    n0 = nt * 64;
  }
  const int k = k0 + grp * 4;
  const int n = n0 + sub * 4;
  unsigned d0[4], d1[4];
#pragma unroll
  for (int i = 0; i < 4; ++i) {
    float4 v = *(const float4*)(src + (size_t)(k + i) * src_ld + n);
    d0[i] = pkrne(v.x * sc, v.y * sc);
    d1[i] = pkrne(v.z * sc, v.w * sc);
  }
  u32x2 r0 = {__builtin_amdgcn_perm(d0[1], d0[0], 0x05040100u),
              __builtin_amdgcn_perm(d0[3], d0[2], 0x05040100u)};
  u32x2 r1 = {__builtin_amdgcn_perm(d0[1], d0[0], 0x07060302u),
              __builtin_amdgcn_perm(d0[3], d0[2], 0x07060302u)};
  u32x2 r2 = {__builtin_amdgcn_perm(d1[1], d1[0], 0x05040100u),
              __builtin_amdgcn_perm(d1[3], d1[2], 0x05040100u)};
  u32x2 r3 = {__builtin_amdgcn_perm(d1[1], d1[0], 0x07060302u),
              __builtin_amdgcn_perm(d1[3], d1[2], 0x07060302u)};
  *(u32x2*)(dst + (size_t)(n + 0) * 256 + k) = r0;
  *(u32x2*)(dst + (size_t)(n + 1) * 256 + k) = r1;
  *(u32x2*)(dst + (size_t)(n + 2) * 256 + k) = r2;
  *(u32x2*)(dst + (size_t)(n + 3) * 256 + k) = r3;
}

// ---------------------------------------------------------------------------
// Fused QKV: D[n][tok] = wT(rows n) x xbf(rows tok). (unchanged, round 6)
// ---------------------------------------------------------------------------
__global__ __launch_bounds__(256) void qkv_kernel(
    const ushort* __restrict__ xbf, const ushort* __restrict__ wT,
    const float* __restrict__ bq, ushort* __restrict__ QG,
    ushort* __restrict__ KG, ushort* __restrict__ VtG) {
  __shared__ __align__(16) ushort Wl[64][40];
  __shared__ __align__(16) ushort Xl[128][40];
  const int t0 = blockIdx.x * 128;
  const int n0 = blockIdx.y * 64;
  const int t = threadIdx.x;
  const int wid = t >> 6, lane = t & 63;
  const int wy = wid >> 1, wx = wid & 1;
  const int quad = lane >> 4, l16 = lane & 15;
  f32x4 acc[2][4] = {};
  const int wr = t >> 2, wsg = t & 3;
  for (int k0 = 0; k0 < 256; k0 += 32) {
    __syncthreads();
    *(uint4*)&Wl[wr][wsg * 8] =
        *(const uint4*)(wT + (size_t)(n0 + wr) * 256 + k0 + wsg * 8);
#pragma unroll
    for (int i = 0; i < 2; ++i) {
      int fid = t + 256 * i, row = fid >> 2, seg = fid & 3;
      *(uint4*)&Xl[row][seg * 8] =
          *(const uint4*)(xbf + (size_t)(t0 + row) * 256 + k0 + seg * 8);
    }
    __syncthreads();
    s16x8 wf[2], xf[4];
#pragma unroll
    for (int i = 0; i < 2; ++i)
      wf[i] = *(const s16x8*)&Wl[32 * wy + 16 * i + l16][quad * 8];
#pragma unroll
    for (int j = 0; j < 4; ++j)
      xf[j] = *(const s16x8*)&Xl[64 * wx + 16 * j + l16][quad * 8];
#pragma unroll
    for (int i = 0; i < 2; ++i)
#pragma unroll
      for (int j = 0; j < 4; ++j) acc[i][j] = MFMA32(wf[i], xf[j], acc[i][j]);
  }
  if (n0 < 512) {
    ushort* dst = (n0 < 256) ? QG : KG;
    const float bsc = (n0 < 256) ? SL2E : 1.f;
#pragma unroll
    for (int i = 0; i < 2; ++i) {
      int nb = n0 + 32 * wy + 16 * i + 4 * quad;
      float4 b4 = *(const float4*)(bq + nb);
      float bx0 = b4.x * bsc, bx1 = b4.y * bsc, bx2 = b4.z * bsc,
            bx3 = b4.w * bsc;
      int h = ((nb & 255) >> 5);
      int dd0 = nb & 31;
#pragma unroll
      for (int j = 0; j < 4; ++j) {
        int tok = t0 + 64 * wx + 16 * j + l16;
        int b = tok >> 12, tokn = tok & 4095;
        u32x2 pk = {pkrne(acc[i][j][0] + bx0, acc[i][j][1] + bx1),
                    pkrne(acc[i][j][2] + bx2, acc[i][j][3] + bx3)};
        *(u32x2*)(dst + ((size_t)(b * 8 + h) * 4096 + tokn) * 32 + dd0) = pk;
      }
    }
  } else {
#pragma unroll
    for (int i = 0; i < 2; ++i) {
      int nb = n0 + 32 * wy + 16 * i + 4 * quad;
      float4 b4 = *(const float4*)(bq + nb);
      float bb[4] = {b4.x, b4.y, b4.z, b4.w};
#pragma unroll
      for (int r = 0; r < 4; ++r) {
        int nn = nb + r - 512;
        int h = nn >> 5, ddv = nn & 31;
        ushort* vrow = VtG + (size_t)(h * 32 + ddv) * 4096;
#pragma unroll
        for (int j = 0; j < 4; ++j) {
          int tok = t0 + 64 * wx + 16 * j + l16;
          int b = tok >> 12, tokn = tok & 4095;
          vrow[(size_t)b * 8 * 32 * 4096 + tokn] = bfr(acc[i][j][r] + bb[r]);
        }
      }
    }
  }
}

// ---------------------------------------------------------------------------
// Flash attention, SPLIT-K x3. Grid 1536 = exactly 6 blocks/CU resident
// (LDS 19456 x 6 = 116.7 of 160 KiB; launch_bounds(256,6) -> 85-reg budget,
// body needs ~80 -> no spill; round 8 showed (256,8)'s 64-reg budget spills
// catastrophically). Block (bh, q128, sp) handles k-tiles [kt0(sp), kt1(sp)),
// ranges {[0,22),[22,43),[43,64)}. No-max softmax => partials additive.
// Partial O stored bf16, partial l f32. QK^T and exp fused per-nb so the
// f32 score regs never stay live across the loop (register pressure).
// ---------------------------------------------------------------------------
__global__ __launch_bounds__(256, 6) void attn_split(
    const ushort* __restrict__ QG, const ushort* __restrict__ KG,
    const ushort* __restrict__ VtG, ushort* __restrict__ OF0,
    ushort* __restrict__ OFb, float* __restrict__ LF) {
  __shared__ __align__(16) ushort Kl[2][64][40];
  __shared__ __align__(16) ushort Vl[2][32][72];
  const int id = blockIdx.x;
  const int bh = (id & 7) * 2 + ((id >> 3) & 1);  // XCD-affine heads
  const int q0 = ((id >> 4) & 31) * 128;
  const int sp = id >> 9;                          // split index 0..2
  const int kt0 = (sp * 64 + 2) / 3;               // {0,22,43}
  const int niter = ((sp + 1) * 64 + 2) / 3 - kt0; // {22,21,21}
  const int t = threadIdx.x;
  const int wid = t >> 6, lane = t & 63;
  const int quad = lane >> 4, l16 = lane & 15;
  const size_t base = (size_t)bh * 4096 * 32;
  const ushort* qp = QG + base;
  const ushort* kp = KG + base;
  const ushort* vp = VtG + base;
  const int qw = q0 + 32 * wid;
  const s16x8 qf0 = *(const s16x8*)(qp + (size_t)(qw + l16) * 32 + quad * 8);
  const s16x8 qf1 = *(const s16x8*)(qp + (size_t)(qw + 16 + l16) * 32 + quad * 8);
  const int kr = t >> 2, ks = t & 3;
  const int vr = t >> 3, vsg = t & 7;
  *(uint4*)&Kl[0][kr][ks * 8] =
      *(const uint4*)(kp + (size_t)(kt0 * 64 + kr) * 32 + ks * 8);
  *(uint4*)&Vl[0][vr][vsg * 8] =
      *(const uint4*)(vp + (size_t)vr * 4096 + kt0 * 64 + vsg * 8);
  const ushort* kpre = kp + (size_t)((kt0 + 1) * 64 + kr) * 32 + ks * 8;
  const ushort* vpre = vp + (size_t)vr * 4096 + (kt0 + 1) * 64 + vsg * 8;
  __syncthreads();
  f32x4 o00 = {}, o01 = {}, o10 = {}, o11 = {}, ol0 = {}, ol1 = {};
  const f32x4 zero = {};
  const s16x4 ones = {(short)0x3F80, (short)0x3F80, (short)0x3F80,
                      (short)0x3F80};
  for (int i = 0; i < niter; ++i) {
    const int cur = i & 1;
    const bool more = (i + 1) < niter;
    uint4 kv, vv;
    if (more) {
      kv = *(const uint4*)kpre;
      vv = *(const uint4*)vpre;
      kpre += 2048;
      vpre += 64;
    }
    // QK^T + exp fused per-nb: score regs live only inside each nb step.
    unsigned pl0[4], ph0[4], pl1[4], ph1[4];
#pragma unroll
    for (int nb = 0; nb < 4; ++nb) {
      s16x8 kf = *(const s16x8*)&Kl[cur][16 * nb + l16][quad * 8];
      f32x4 s0 = MFMA32(kf, qf0, zero);
      f32x4 s1 = MFMA32(kf, qf1, zero);
      pl0[nb] = pktrunc(EXP2F(s0[0]), EXP2F(s0[1]));
      ph0[nb] = pktrunc(EXP2F(s0[2]), EXP2F(s0[3]));
      pl1[nb] = pktrunc(EXP2F(s1[0]), EXP2F(s1[1]));
      ph1[nb] = pktrunc(EXP2F(s1[2]), EXP2F(s1[3]));
    }
#pragma unroll
    for (int nb = 0; nb < 4; ++nb) {
      u32x2 pu0 = {pl0[nb], ph0[nb]};
      u32x2 pu1 = {pl1[nb], ph1[nb]};
      s16x4 pv0 = __builtin_bit_cast(s16x4, pu0);
      s16x4 pv1 = __builtin_bit_cast(s16x4, pu1);
      s16x4 va = *(const s16x4*)&Vl[cur][l16][16 * nb + quad * 4];
      s16x4 vb = *(const s16x4*)&Vl[cur][16 + l16][16 * nb + quad * 4];
      o00 = MFMA16K(va, pv0, o00);
      o01 = MFMA16K(vb, pv0, o01);
      o10 = MFMA16K(va, pv1, o10);
      o11 = MFMA16K(vb, pv1, o11);
      ol0 = MFMA16K(ones, pv0, ol0);
      ol1 = MFMA16K(ones, pv1, ol1);
    }
    if (more) {
      *(uint4*)&Kl[cur ^ 1][kr][ks * 8] = kv;
      *(uint4*)&Vl[cur ^ 1][vr][vsg * 8] = vv;
    }
    __syncthreads();
  }
  // Store un-normalized bf16 partial O + f32 partial l.
  ushort* OFs = (sp == 0) ? OF0 : OFb + (size_t)(sp - 1) * 2097152;
  float* LFs = LF + (size_t)sp * 65536;
  const int tok0 = qw + l16;
  const size_t ob0 = ((size_t)bh * 4096 + tok0) * 32;
  const size_t ob1 = ob0 + (size_t)16 * 32;
  u32x2 w00 = {pkrne(o00[0], o00[1]), pkrne(o00[2], o00[3])};
  u32x2 w01 = {pkrne(o01[0], o01[1]), pkrne(o01[2], o01[3])};
  u32x2 w10 = {pkrne(o10[0], o10[1]), pkrne(o10[2], o10[3])};
  u32x2 w11 = {pkrne(o11[0], o11[1]), pkrne(o11[2], o11[3])};
  *(u32x2*)(OFs + ob0 + 4 * quad) = w00;
  *(u32x2*)(OFs + ob0 + 16 + 4 * quad) = w01;
  *(u32x2*)(OFs + ob1 + 4 * quad) = w10;
  *(u32x2*)(OFs + ob1 + 16 + 4 * quad) = w11;
  if (quad == 0) {
    LFs[(size_t)bh * 4096 + tok0] = ol0[0];
    LFs[(size_t)bh * 4096 + tok0 + 16] = ol1[0];
  }
}

// ---------------------------------------------------------------------------
// Out-proj with fused 3-way split-combine + normalization in the staging.
// ---------------------------------------------------------------------------
__global__ __launch_bounds__(256) void proj_split(
    const ushort* __restrict__ OF0, const ushort* __restrict__ OFb,
    const float* __restrict__ LF, const ushort* __restrict__ woT,
    const float* __restrict__ bo, float* __restrict__ out) {
  __shared__ __align__(16) ushort Wl[64][40];
  __shared__ __align__(16) ushort Xl[128][40];
  const int t0 = blockIdx.x * 128;
  const int c0 = blockIdx.y * 64;
  const int t = threadIdx.x;
  const int wid = t >> 6, lane = t & 63;
  const int wy = wid >> 1, wx = wid & 1;
  const int quad = lane >> 4, l16 = lane & 15;
  f32x4 acc[2][4] = {};
  const int wr = t >> 2, wsg = t & 3;
  const int c8 = (t & 7) * 4;  // dd column (4 ushorts)
  for (int k0 = 0; k0 < 256; k0 += 32) {
    __syncthreads();
    *(uint4*)&Wl[wr][wsg * 8] =
        *(const uint4*)(woT + (size_t)(c0 + wr) * 256 + k0 + wsg * 8);
    const int hh = k0 >> 5;
#pragma unroll
    for (int p = 0; p < 4; ++p) {
      int row = 32 * p + (t >> 3);
      int tok = t0 + row, bb = tok >> 12, tokn = tok & 4095;
      size_t ro = (size_t)(bb * 8 + hh) * 4096 + tokn;
      size_t oi = ro * 32 + c8;
      uint2 a0 = *(const uint2*)(OF0 + oi);
      uint2 a1 = *(const uint2*)(OFb + oi);
      uint2 a2 = *(const uint2*)(OFb + 2097152 + oi);
      float l = LF[ro] + LF[65536 + ro] + LF[131072 + ro];
      float inv = RCPF(l);
      f32x4 s;
      s[0] = bflo(a0.x) + bflo(a1.x) + bflo(a2.x);
      s[1] = bfhi(a0.x) + bfhi(a1.x) + bfhi(a2.x);
      s[2] = bflo(a0.y) + bflo(a1.y) + bflo(a2.y);
      s[3] = bfhi(a0.y) + bfhi(a1.y) + bfhi(a2.y);
      s *= inv;
      u32x2 pk = {pkrne(s[0], s[1]), pkrne(s[2], s[3])};
      *(u32x2*)&Xl[row][c8] = pk;
    }
    __syncthreads();
    s16x8 wf[2], xf[4];
#pragma unroll
    for (int i = 0; i < 2; ++i)
      wf[i] = *(const s16x8*)&Wl[32 * wy + 16 * i + l16][quad * 8];
#pragma unroll
    for (int j = 0; j < 4; ++j)
      xf[j] = *(const s16x8*)&Xl[64 * wx + 16 * j + l16][quad * 8];
#pragma unroll
    for (int i = 0; i < 2; ++i)
#pragma unroll
      for (int j = 0; j < 4; ++j) acc[i][j] = MFMA32(wf[i], xf[j], acc[i][j]);
  }
#pragma unroll
  for (int i = 0; i < 2; ++i) {
    int cb = c0 + 32 * wy + 16 * i + 4 * quad;
    float4 b4 = *(const float4*)(bo + cb);
    float bb[4] = {b4.x, b4.y, b4.z, b4.w};
#pragma unroll
    for (int j = 0; j < 4; ++j) {
      int tok = t0 + 64 * wx + 16 * j + l16;
      int b = tok >> 12, tokn = tok & 4095;
#pragma unroll
      for (int r = 0; r < 4; ++r)
        out[((size_t)(b * 256 + cb + r)) * 4096 + tokn] = acc[i][j][r] + bb[r];
    }
  }
}

extern "C" void kernel_launch(void* const* d_in, const int* in_sizes, int n_in,
                              void* d_out, int out_size, void* d_ws, size_t ws_size,
                              hipStream_t stream) {
  (void)in_sizes; (void)n_in; (void)out_size; (void)ws_size;
  const float* x = (const float*)d_in[0];
  const float* wq = (const float*)d_in[1];
  const float* bq = (const float*)d_in[2];
  const float* wo = (const float*)d_in[3];
  const float* bo = (const float*)d_in[4];
  float* out = (float*)d_out;
  ushort* ws = (ushort*)d_ws;
  // ws layout (26.5 MB used; ws_size >= 30.9 MB verified rounds 7-8):
  ushort* xbf = ws;                    // [8192][256]  (dead after qkv)
  ushort* OF0 = ws;                    // split0 partial O overlays dead xbf
  ushort* QG  = ws + 2097152;          // [2][8][4096][32]
  ushort* KG  = ws + 4194304;
  ushort* VtG = ws + 6291456;          // [2][8][32][4096]
  ushort* wT  = ws + 8388608;          // [768][256]
  ushort* woT = ws + 8585216;          // [256][256]
  ushort* OFb = ws + 8650752;          // splits 1,2: 2 x 2,097,152 ushorts
  float* LF = (float*)(ws + 12845056); // [3][16][4096] f32
  prep_kernel<<<576, 256, 0, stream>>>(x, wq, wo, xbf, wT, woT);
  qkv_kernel<<<dim3(64, 12), 256, 0, stream>>>(xbf, wT, bq, QG, KG, VtG);
  attn_split<<<1536, 256, 0, stream>>>(QG, KG, VtG, OF0, OFb, LF);
  proj_split<<<dim3(64, 4), 256, 0, stream>>>(OF0, OFb, LF, woT, bo, out);
}